// Round 6
// baseline (166.744 us; speedup 1.0000x reference)
//
#include <hip/hip_runtime.h>

typedef unsigned short u16;
typedef unsigned char u8;
typedef unsigned int u32;
typedef __bf16 bf16x8 __attribute__((ext_vector_type(8)));
typedef float  f32x16 __attribute__((ext_vector_type(16)));
typedef int    i32x4  __attribute__((ext_vector_type(4)));
typedef int    i32x16 __attribute__((ext_vector_type(16)));

#define NB 4
#define NN 4096
#define ND 256

#define QPV (127.0f / 4.5f)        // pv quant scale
#define DPV (4.5f / 16129.0f)      // O dequant
#define QST (127.0f / 4.6f)        // state quant scale
#define DST (4.6f / 16129.0f)      // ds dequant

__device__ __forceinline__ u16 f2bf(float x) { return __builtin_bit_cast(u16, (__bf16)x); }

typedef __attribute__((address_space(1))) const u32 gas_u32;
typedef __attribute__((address_space(3))) u32 las_u32;
__device__ __forceinline__ void async_ld16(void* lds, const void* g) {
    __builtin_amdgcn_global_load_lds((gas_u32*)g, (las_u32*)lds, 16, 0, 0);
}

__device__ __forceinline__ int q8(float x) {
    x = fminf(fmaxf(x, -127.0f), 127.0f);
    return (int)rintf(x);
}
__device__ __forceinline__ u32 pack4(int a, int b, int c, int d) {
    return (u32)(a & 255) | ((u32)(b & 255) << 8) | ((u32)(c & 255) << 16) | ((u32)d << 24);
}

// ws layout:
//  kq8 : [b*128+strip][s8][lane64][16B]        i8 val frags (A/B operand), 4 MB
//  vp8 : [b*128+strip][slot9][lane64][16B]     i8 frags: slot0..7 = pv^T ets, slot8 = state bcast, 4.5 MB
//  kq  : [b*128+strip][s16][lane64][8]         bf16 val frags (k_pv input), 8 MB
//  wv  : [es8][s16][lane64][8]                 bf16 Wv^T frags, 128 KB
//  srow: [b*4096+n] f32 = rowmax/127, 64 KB

// ---- prep: val pack (bf16 + per-row-scaled i8 + srow), state bcast i8, Wv^T pack ----
__global__ __launch_bounds__(256) void k_prep(const float* __restrict__ val,
                                              const float* __restrict__ state,
                                              const float* __restrict__ Wv,
                                              u16* __restrict__ kq, u8* __restrict__ kq8,
                                              float* __restrict__ srow,
                                              u8* __restrict__ vp8, u16* __restrict__ wv) {
    int tid = threadIdx.x;
    int bid = blockIdx.x;
    if (bid < 512) {
        __shared__ float t[32 * 257];
        __shared__ float rmax[32];
        const float* src = val + (size_t)bid * 32 * 256;
        #pragma unroll
        for (int k = 0; k < 8; k++) {
            int idx = tid + k * 256;
            int row = idx >> 6, c4 = idx & 63;
            float4 v = *(const float4*)(src + row * 256 + c4 * 4);
            float* p = t + row * 257 + c4 * 4;
            p[0] = v.x; p[1] = v.y; p[2] = v.z; p[3] = v.w;
        }
        __syncthreads();
        // per-row max|.|
        {
            int row = tid >> 3, seg = tid & 7;
            float m = 0.0f;
            #pragma unroll
            for (int i = 0; i < 32; i++) m = fmaxf(m, fabsf(t[row * 257 + seg + i * 8]));
            m = fmaxf(m, __shfl_down(m, 4));
            m = fmaxf(m, __shfl_down(m, 2));
            m = fmaxf(m, __shfl_down(m, 1));
            if (seg == 0) {
                m = fmaxf(m, 1e-20f);
                rmax[row] = m;
                srow[bid * 32 + row] = m * (1.0f / 127.0f);
            }
        }
        __syncthreads();
        // bf16 frags (k_pv input)
        u16* dst = kq + (size_t)bid * 16 * 512;
        #pragma unroll
        for (int k = 0; k < 4; k++) {
            int flat = tid + k * 256;
            int s = flat >> 6, l = flat & 63;
            int l31 = l & 31, h = l >> 5;
            const float* p = t + l31 * 257 + s * 16 + h * 8;
            union { u16 o[8]; uint4 q; } u;
            #pragma unroll
            for (int j = 0; j < 8; j++) u.o[j] = f2bf(p[j]);
            *(uint4*)(dst + (size_t)flat * 8) = u.q;
        }
        // i8 frags with per-row scale
        u8* dst8 = kq8 + (size_t)bid * 8192;
        #pragma unroll
        for (int k = 0; k < 2; k++) {
            int flat = tid + k * 256;
            int s = flat >> 6, l = flat & 63;
            int l31 = l & 31, h = l >> 5;
            float r127 = 127.0f / rmax[l31];
            const float* p = t + l31 * 257 + s * 32 + h * 16;
            union { u8 b[16]; i32x4 v; } u;
            #pragma unroll
            for (int j = 0; j < 16; j++) u.b[j] = (u8)(q8(p[j] * r127) & 255);
            *(i32x4*)(dst8 + (size_t)flat * 16) = u.v;
        }
    } else if (bid < 516) {
        int b = bid - 512;
        __shared__ u8 qs[4096];
        #pragma unroll
        for (int k = 0; k < 16; k++) {
            int i = tid + k * 256;
            qs[i] = (u8)(q8(state[b * 4096 + i] * QST) & 255);
        }
        __syncthreads();
        #pragma unroll
        for (int k = 0; k < 32; k++) {
            int chunk = tid + k * 256;                 // strip(128) x lane(64)
            int strip = chunk >> 6, lane = chunk & 63, h = (lane >> 5) & 1;
            i32x4 v = *(const i32x4*)(qs + strip * 32 + h * 16);
            *(i32x4*)(vp8 + ((size_t)((b * 128 + strip) * 9 + 8)) * 1024 + (chunk & 63) * 16) = v;
        }
    } else {
        __shared__ u16 t2[256 * 33];
        int es = bid - 516, e0 = es * 32;
        #pragma unroll
        for (int k = 0; k < 8; k++) {
            int idx = tid + k * 256;
            int row = idx >> 3, c4 = idx & 7;
            float4 v = *(const float4*)(Wv + row * 256 + e0 + c4 * 4);
            u16* p = t2 + row * 33 + c4 * 4;
            p[0] = f2bf(v.x); p[1] = f2bf(v.y); p[2] = f2bf(v.z); p[3] = f2bf(v.w);
        }
        __syncthreads();
        u16* dst = wv + (size_t)es * 16 * 512;
        #pragma unroll
        for (int k = 0; k < 4; k++) {
            int flat = tid + k * 256;
            int s = flat >> 6, l = flat & 63;
            int l31 = l & 31, h = l >> 5;
            union { u16 o[8]; uint4 q; } u;
            #pragma unroll
            for (int j = 0; j < 8; j++) u.o[j] = t2[(s * 16 + h * 8 + j) * 33 + l31];
            *(uint4*)(dst + (size_t)flat * 8) = u.q;
        }
    }
}

// ---- pv^T = Wv^T x val^T (bf16 MFMA) -> i8 B-operand frags, barrier-free ----
__global__ __launch_bounds__(256) void k_pv(const u16* __restrict__ kq, const u16* __restrict__ wv,
                                            u8* __restrict__ vp8) {
    __shared__ u8 tp[4][32 * 48];
    int tid = threadIdx.x;
    int w = tid >> 6, lane = tid & 63;
    int l31 = lane & 31, h = lane >> 5;
    int wid = blockIdx.x * 4 + w;
    int bb = wid >> 8, es = (wid >> 5) & 7, qb = wid & 31;
    const u16* wvb = wv + (size_t)(es * 16) * 512 + lane * 8;
    const u16* kqb = kq + ((size_t)(bb * 128 + qb * 4) * 16) * 512 + lane * 8;
    f32x16 acc[4] = {};
    for (int s = 0; s < 16; s++) {
        bf16x8 af = *(const bf16x8*)(wvb + s * 512);
        #pragma unroll
        for (int qt = 0; qt < 4; qt++) {
            bf16x8 bfr = *(const bf16x8*)(kqb + (size_t)(qt * 16 + s) * 512);
            acc[qt] = __builtin_amdgcn_mfma_f32_32x32x16_bf16(af, bfr, acc[qt], 0, 0, 0);
        }
    }
    u8* myp = tp[w];
    #pragma unroll
    for (int qt = 0; qt < 4; qt++) {
        #pragma unroll
        for (int r = 0; r < 16; r++) {
            int erow = (r & 3) + 8 * (r >> 2) + 4 * h;
            myp[erow * 48 + l31] = (u8)(q8(acc[qt][r] * QPV) & 255);
        }
        // within-wave LDS RAW: compiler inserts lgkmcnt waits; no cross-wave sharing
        i32x4 v = *(const i32x4*)(myp + l31 * 48 + h * 16);
        *(i32x4*)(vp8 + ((size_t)((bb * 128 + qb * 4 + qt) * 9 + es)) * 1024 + lane * 16) = v;
    }
}

__device__ __forceinline__ void stage_tile(u8* dstLds, const u8* src, int tid) {
    #pragma unroll
    for (int k = 0; k < 9; k++) {                      // 2304 chunks of 16B = 36 KB
        int chunk = tid + k * 256;
        async_ld16(dstLds + (size_t)chunk * 16, src + (size_t)chunk * 16);
    }
}

// ---- main: K direct-from-L2, V+state LDS dbuf, 4 waves = 4 mq, q=32/block ----
__global__ __launch_bounds__(256, 2) void k_main(const u8* __restrict__ kq8,
                                                 const u8* __restrict__ vp8,
                                                 const float* __restrict__ srow,
                                                 float* __restrict__ ds_out,
                                                 float* __restrict__ dval_out) {
    __shared__ u8 stage[2 * 36864];                    // dbuf V+state tiles (4 strips x 9 KB)
    __shared__ int dsqi[4][32];

    int tid = threadIdx.x;
    int mq = tid >> 6, lane = tid & 63;
    int l31 = lane & 31, h = lane >> 5;

    int id = blockIdx.x;                               // [0,512)
    int xcd = id & 7;
    int bb = xcd >> 1;                                 // batch pinned per XCD pair
    int t7 = ((xcd & 1) << 6) | (id >> 3);             // q-strip [0,128)
    int q0 = t7 * 32;

    // resident Q frags (B operand, i8): 32 VGPR
    i32x4 qf[8];
    {
        const u8* qsrc = kq8 + (size_t)(bb * 128 + t7) * 8192 + lane * 16;
        #pragma unroll
        for (int s = 0; s < 8; s++) qf[s] = *(const i32x4*)(qsrc + (size_t)s * 1024);
    }
    float srq = srow[bb * 4096 + q0 + l31];

    i32x16 oacc[8] = {};
    i32x16 dsa = {};

    stage_tile(stage, vp8 + (size_t)(bb * 128) * 9216, tid);
    __syncthreads();

    for (int mt = 0; mt < 32; mt++) {
        u8* buf = stage + (mt & 1) * 36864;
        if (mt + 1 < 32)
            stage_tile(stage + ((mt + 1) & 1) * 36864,
                       vp8 + (size_t)(bb * 128 + (mt + 1) * 4) * 9216, tid);

        // S^T = K x Q^T, K frags direct from L2 (packed, lane-linear)
        const u8* kb = kq8 + (size_t)(bb * 128 + mt * 4 + mq) * 8192 + lane * 16;
        i32x16 sacc = {};
        #pragma unroll
        for (int g = 0; g < 2; g++) {
            i32x4 kf[4];
            #pragma unroll
            for (int s = 0; s < 4; s++) kf[s] = *(const i32x4*)(kb + (size_t)(g * 4 + s) * 1024);
            #pragma unroll
            for (int s = 0; s < 4; s++)
                sacc = __builtin_amdgcn_mfma_i32_32x32x32_i8(kf[s], qf[g * 4 + s], sacc, 0, 0, 0);
        }

        // per-row dequant scales for this wave's m chunk
        const float* srm = srow + bb * 4096 + mt * 128 + mq * 32;
        float4 sg[4];
        #pragma unroll
        for (int g = 0; g < 4; g++) sg[g] = *(const float4*)(srm + g * 8 + h * 4);

        // dequant -> softsign -> quantize P to i8
        int ai[16];
        #pragma unroll
        for (int r = 0; r < 16; r++) {
            float sm = ((const float*)&sg[r >> 2])[r & 3] * srq;
            float xf = (float)sacc[r];
            float d = fmaf(fabsf(xf), sm, 1.0f);
            float p = xf * sm * 127.0f * __builtin_amdgcn_rcpf(d);
            ai[r] = (int)rintf(p);
        }
        u32 w0 = pack4(ai[0], ai[1], ai[2], ai[3]);
        u32 w1 = pack4(ai[4], ai[5], ai[6], ai[7]);
        u32 w2 = pack4(ai[8], ai[9], ai[10], ai[11]);
        u32 w3 = pack4(ai[12], ai[13], ai[14], ai[15]);
        u32 x0 = (u32)__shfl_xor((int)w0, 32);
        u32 x1 = (u32)__shfl_xor((int)w1, 32);
        u32 x2 = (u32)__shfl_xor((int)w2, 32);
        u32 x3 = (u32)__shfl_xor((int)w3, 32);
        union { u32 wd[4]; i32x4 v; } pu;
        if (h == 0) { pu.wd[0] = w0; pu.wd[1] = x0; pu.wd[2] = w1; pu.wd[3] = x1; }
        else        { pu.wd[0] = x2; pu.wd[1] = w2; pu.wd[2] = x3; pu.wd[3] = w3; }
        i32x4 pf = pu.v;

        // O += P x Vt (8 ets) + ds (state-broadcast frag), all from current LDS buf
        const u8* vb = buf + mq * 9216;
        #pragma unroll
        for (int et = 0; et < 8; et++) {
            i32x4 vf = *(const i32x4*)(vb + et * 1024 + lane * 16);
            oacc[et] = __builtin_amdgcn_mfma_i32_32x32x32_i8(pf, vf, oacc[et], 0, 0, 0);
        }
        {
            i32x4 sf = *(const i32x4*)(vb + 8 * 1024 + lane * 16);
            dsa = __builtin_amdgcn_mfma_i32_32x32x32_i8(pf, sf, dsa, 0, 0, 0);
        }
        __syncthreads();                               // one barrier/tile
    }

    // ---- epilogue: serial mq-chain reduction in LDS (i32 exact) ----
    if (l31 == 0) {
        #pragma unroll
        for (int r = 0; r < 16; r++) dsqi[mq][(r & 3) + 8 * (r >> 2) + 4 * h] = dsa[r];
    }
    int* red = (int*)stage;                            // 32 rows x 256 cols i32 = 32 KB
    if (mq == 3) {
        #pragma unroll
        for (int et = 0; et < 8; et++)
            #pragma unroll
            for (int r = 0; r < 16; r++) {
                int row = (r & 3) + 8 * (r >> 2) + 4 * h;
                red[row * 256 + et * 32 + l31] = oacc[et][r];
            }
    }
    __syncthreads();
    if (mq == 2) {
        #pragma unroll
        for (int et = 0; et < 8; et++)
            #pragma unroll
            for (int r = 0; r < 16; r++) {
                int row = (r & 3) + 8 * (r >> 2) + 4 * h;
                red[row * 256 + et * 32 + l31] += oacc[et][r];
            }
    }
    __syncthreads();
    if (mq == 1) {
        #pragma unroll
        for (int et = 0; et < 8; et++)
            #pragma unroll
            for (int r = 0; r < 16; r++) {
                int row = (r & 3) + 8 * (r >> 2) + 4 * h;
                red[row * 256 + et * 32 + l31] += oacc[et][r];
            }
    }
    __syncthreads();
    if (mq == 0) {
        #pragma unroll
        for (int et = 0; et < 8; et++)
            #pragma unroll
            for (int r = 0; r < 16; r++) {
                int row = (r & 3) + 8 * (r >> 2) + 4 * h;
                int sum = oacc[et][r] + red[row * 256 + et * 32 + l31];
                dval_out[((size_t)(bb * 4096 + q0 + row)) * 256 + et * 32 + l31] = (float)sum * DPV;
            }
        if (lane < 32) {
            int d = dsqi[0][lane] + dsqi[1][lane] + dsqi[2][lane] + dsqi[3][lane];
            ds_out[bb * 4096 + q0 + lane] = (float)d * DST;
        }
    }
}

extern "C" void kernel_launch(void* const* d_in, const int* in_sizes, int n_in,
                              void* d_out, int out_size, void* d_ws, size_t ws_size,
                              hipStream_t stream) {
    const float* val   = (const float*)d_in[0];
    const float* state = (const float*)d_in[1];
    const float* Wv    = (const float*)d_in[2];

    float* ds_out   = (float*)d_out;
    float* dval_out = ds_out + NB * NN;

    u8*  kq8 = (u8*)d_ws;                                      // 4 MB
    u8*  vp8 = kq8 + (size_t)NB * NN * ND;                     // 4.5 MB
    u16* kq  = (u16*)(vp8 + (size_t)NB * 128 * 9216);          // 8 MB
    u16* wv  = kq + (size_t)NB * NN * ND;                      // 128 KB
    float* srow = (float*)(wv + 8 * 16 * 512);                 // 64 KB

    k_prep<<<524, 256, 0, stream>>>(val, state, Wv, kq, kq8, srow, vp8, wv);
    k_pv<<<256, 256, 0, stream>>>(kq, wv, vp8);
    k_main<<<512, 256, 0, stream>>>(kq8, vp8, srow, ds_out, dval_out);
}

// Round 8
// 149.521 us; speedup vs baseline: 1.1152x; 1.1152x over previous
//
#include <hip/hip_runtime.h>

typedef unsigned short u16;
typedef unsigned char u8;
typedef unsigned int u32;
typedef __bf16 bf16x8 __attribute__((ext_vector_type(8)));
typedef float  f32x16 __attribute__((ext_vector_type(16)));
typedef int    i32x4  __attribute__((ext_vector_type(4)));
typedef int    i32x16 __attribute__((ext_vector_type(16)));

#define NB 4
#define NN 4096
#define ND 256

#define QPV (127.0f / 4.5f)        // pv quant scale
#define DPV (4.5f / 16129.0f)      // O dequant
#define QST (127.0f / 4.6f)        // state quant scale
#define DST (4.6f / 16129.0f)      // ds dequant
#define MAGIC 12582912.0f          // 1.5*2^23: fma(x,s,MAGIC) -> low byte = int8(x*s) rne

__device__ __forceinline__ u16 f2bf(float x) { return __builtin_bit_cast(u16, (__bf16)x); }
__device__ __forceinline__ u32 fbits(float x) { return __builtin_bit_cast(u32, x); }

// pack low bytes of 4 magic-biased floats into one dword (3 x v_perm_b32)
__device__ __forceinline__ u32 packlow4(float a, float b, float c, float d) {
    u32 p = __builtin_amdgcn_perm(fbits(b), fbits(a), 0x00000400u);
    u32 q = __builtin_amdgcn_perm(fbits(d), fbits(c), 0x00000400u);
    return __builtin_amdgcn_perm(q, p, 0x05040100u);
}

typedef __attribute__((address_space(1))) const u32 gas_u32;
typedef __attribute__((address_space(3))) u32 las_u32;
__device__ __forceinline__ void async_ld16(void* lds, const void* g) {
    __builtin_amdgcn_global_load_lds((gas_u32*)g, (las_u32*)lds, 16, 0, 0);
}

// ws layout:
//  kq8 : [b*128+strip][s8][lane64][16B]    i8 val frags (A/B operand), 4 MB
//  vp8 : [b*128+strip][slot9][lane64][16B] i8 frags: slot0..7 = pv^T, slot8 = state bcast, 4.5 MB
//  kq  : [b*128+strip][s16][lane64][8]     bf16 val frags (k_pv input), 8 MB
//  wv  : [es8][s16][lane64][8]             bf16 Wv^T frags, 128 KB
//  srow: [b*4096+n] f32 = rowmax/127, 64 KB

__global__ __launch_bounds__(256) void k_prep(const float* __restrict__ val,
                                              const float* __restrict__ state,
                                              const float* __restrict__ Wv,
                                              u16* __restrict__ kq, u8* __restrict__ kq8,
                                              float* __restrict__ srow,
                                              u8* __restrict__ vp8, u16* __restrict__ wv) {
    int tid = threadIdx.x;
    int bid = blockIdx.x;
    if (bid < 512) {
        __shared__ float t[32 * 257];
        __shared__ float rmax[32];
        const float* src = val + (size_t)bid * 32 * 256;
        #pragma unroll
        for (int k = 0; k < 8; k++) {
            int idx = tid + k * 256;
            int row = idx >> 6, c4 = idx & 63;
            float4 v = *(const float4*)(src + row * 256 + c4 * 4);
            float* p = t + row * 257 + c4 * 4;
            p[0] = v.x; p[1] = v.y; p[2] = v.z; p[3] = v.w;
        }
        __syncthreads();
        {
            int row = tid >> 3, seg = tid & 7;
            float m = 0.0f;
            #pragma unroll
            for (int i = 0; i < 32; i++) m = fmaxf(m, fabsf(t[row * 257 + seg + i * 8]));
            m = fmaxf(m, __shfl_down(m, 4));
            m = fmaxf(m, __shfl_down(m, 2));
            m = fmaxf(m, __shfl_down(m, 1));
            if (seg == 0) {
                m = fmaxf(m, 1e-20f);
                rmax[row] = m;
                srow[bid * 32 + row] = m * (1.0f / 127.0f);
            }
        }
        __syncthreads();
        u16* dst = kq + (size_t)bid * 16 * 512;
        #pragma unroll
        for (int k = 0; k < 4; k++) {
            int flat = tid + k * 256;
            int s = flat >> 6, l = flat & 63;
            int l31 = l & 31, h = l >> 5;
            const float* p = t + l31 * 257 + s * 16 + h * 8;
            union { u16 o[8]; uint4 q; } u;
            #pragma unroll
            for (int j = 0; j < 8; j++) u.o[j] = f2bf(p[j]);
            *(uint4*)(dst + (size_t)flat * 8) = u.q;
        }
        // i8 frags, per-row scale; |val|<=rmax so no clamp needed
        u8* dst8 = kq8 + (size_t)bid * 8192;
        #pragma unroll
        for (int k = 0; k < 2; k++) {
            int flat = tid + k * 256;
            int s = flat >> 6, l = flat & 63;
            int l31 = l & 31, h = l >> 5;
            float r127 = 127.0f / rmax[l31];
            const float* p = t + l31 * 257 + s * 32 + h * 16;
            u32 d[4];
            #pragma unroll
            for (int g = 0; g < 4; g++)
                d[g] = packlow4(fmaf(p[4 * g + 0], r127, MAGIC), fmaf(p[4 * g + 1], r127, MAGIC),
                                fmaf(p[4 * g + 2], r127, MAGIC), fmaf(p[4 * g + 3], r127, MAGIC));
            *(uint4*)(dst8 + (size_t)flat * 16) = make_uint4(d[0], d[1], d[2], d[3]);
        }
    } else if (bid < 516) {
        int b = bid - 512;
        __shared__ u8 qs[4096];
        #pragma unroll
        for (int k = 0; k < 16; k++) {
            int i = tid + k * 256;
            float x = fminf(fmaxf(state[b * 4096 + i] * QST, -127.0f), 127.0f);
            qs[i] = (u8)(fbits(x + MAGIC) & 255);
        }
        __syncthreads();
        #pragma unroll
        for (int k = 0; k < 32; k++) {
            int chunk = tid + k * 256;
            int strip = chunk >> 6, lane = chunk & 63, h = (lane >> 5) & 1;
            i32x4 v = *(const i32x4*)(qs + strip * 32 + h * 16);
            *(i32x4*)(vp8 + ((size_t)((b * 128 + strip) * 9 + 8)) * 1024 + (chunk & 63) * 16) = v;
        }
    } else {
        __shared__ u16 t2[256 * 33];
        int es = bid - 516, e0 = es * 32;
        #pragma unroll
        for (int k = 0; k < 8; k++) {
            int idx = tid + k * 256;
            int row = idx >> 3, c4 = idx & 7;
            float4 v = *(const float4*)(Wv + row * 256 + e0 + c4 * 4);
            u16* p = t2 + row * 33 + c4 * 4;
            p[0] = f2bf(v.x); p[1] = f2bf(v.y); p[2] = f2bf(v.z); p[3] = f2bf(v.w);
        }
        __syncthreads();
        u16* dst = wv + (size_t)es * 16 * 512;
        #pragma unroll
        for (int k = 0; k < 4; k++) {
            int flat = tid + k * 256;
            int s = flat >> 6, l = flat & 63;
            int l31 = l & 31, h = l >> 5;
            union { u16 o[8]; uint4 q; } u;
            #pragma unroll
            for (int j = 0; j < 8; j++) u.o[j] = t2[(s * 16 + h * 8 + j) * 33 + l31];
            *(uint4*)(dst + (size_t)flat * 8) = u.q;
        }
    }
}

// ---- pv^T = Wv^T x val^T (bf16 MFMA) -> i8 B-operand frags, barrier-free ----
__global__ __launch_bounds__(256) void k_pv(const u16* __restrict__ kq, const u16* __restrict__ wv,
                                            u8* __restrict__ vp8) {
    __shared__ u8 tp[4][32 * 48];
    int tid = threadIdx.x;
    int w = tid >> 6, lane = tid & 63;
    int l31 = lane & 31, h = lane >> 5;
    int wid = blockIdx.x * 4 + w;
    int bb = wid >> 8, es = (wid >> 5) & 7, qb = wid & 31;
    const u16* wvb = wv + (size_t)(es * 16) * 512 + lane * 8;
    const u16* kqb = kq + ((size_t)(bb * 128 + qb * 4) * 16) * 512 + lane * 8;
    f32x16 acc[4] = {};
    for (int s = 0; s < 16; s++) {
        bf16x8 af = *(const bf16x8*)(wvb + s * 512);
        #pragma unroll
        for (int qt = 0; qt < 4; qt++) {
            bf16x8 bfr = *(const bf16x8*)(kqb + (size_t)(qt * 16 + s) * 512);
            acc[qt] = __builtin_amdgcn_mfma_f32_32x32x16_bf16(af, bfr, acc[qt], 0, 0, 0);
        }
    }
    u8* myp = tp[w];
    #pragma unroll
    for (int qt = 0; qt < 4; qt++) {
        #pragma unroll
        for (int r = 0; r < 16; r++) {
            int erow = (r & 3) + 8 * (r >> 2) + 4 * h;
            float x = fminf(fmaxf(acc[qt][r] * QPV, -127.0f), 127.0f);
            myp[erow * 48 + l31] = (u8)(fbits(x + MAGIC) & 255);
        }
        i32x4 v = *(const i32x4*)(myp + l31 * 48 + h * 16);
        *(i32x4*)(vp8 + ((size_t)((bb * 128 + qb * 4 + qt) * 9 + es)) * 1024 + lane * 16) = v;
    }
}

// wave-private 9 KB stage (V slots 0..7 + state slot 8)
__device__ __forceinline__ void stage_wave(u8* dst, const u8* src, int lane) {
    #pragma unroll
    for (int k = 0; k < 9; k++) {
        int c = lane + k * 64;
        async_ld16(dst + (size_t)c * 16, src + (size_t)c * 16);
    }
}

// ---- main: barrier-free loop; K direct from L2 (issued BEFORE prefetch -> vmcnt leaves it in flight) ----
__global__ __launch_bounds__(256, 2) void k_main(const u8* __restrict__ kq8,
                                                 const u8* __restrict__ vp8,
                                                 const float* __restrict__ srow,
                                                 float* __restrict__ ds_out,
                                                 float* __restrict__ dval_out) {
    __shared__ u8 stage[2][4][9216];           // wave-private dbuf slices
    __shared__ int dsqi[4][32];

    int tid = threadIdx.x;
    int mq = tid >> 6, lane = tid & 63;
    int l31 = lane & 31, h = lane >> 5;

    int id = blockIdx.x;                       // [0,512)
    int xcd = id & 7;
    int bb = xcd >> 1;
    int t7 = ((xcd & 1) << 6) | (id >> 3);     // q-strip [0,128)
    int q0 = t7 * 32;
    size_t bbase = (size_t)bb * 128;

    i32x4 qf[8];
    {
        const u8* qsrc = kq8 + (bbase + t7) * 8192 + lane * 16;
        #pragma unroll
        for (int s = 0; s < 8; s++) qf[s] = *(const i32x4*)(qsrc + (size_t)s * 1024);
    }
    float srq = srow[bb * 4096 + q0 + l31];

    i32x16 oacc[8] = {};
    i32x16 dsa = {};

    stage_wave(stage[0][mq], vp8 + (bbase + mq) * 9216, lane);

    for (int mt = 0; mt < 32; mt++) {
        // 1) K frags (global/L2) — issued FIRST so their wait leaves prefetch in flight
        const u8* kb = kq8 + (bbase + mt * 4 + mq) * 8192 + lane * 16;
        i32x4 kf[8];
        #pragma unroll
        for (int s = 0; s < 8; s++) kf[s] = *(const i32x4*)(kb + (size_t)s * 1024);
        // 2) per-row m scales
        const float* srm = srow + bb * 4096 + mt * 128 + mq * 32;
        float4 sg[4];
        #pragma unroll
        for (int g = 0; g < 4; g++) sg[g] = *(const float4*)(srm + g * 8 + h * 4);
        // 3) prefetch next tile into the other wave-private buffer (no loop barrier)
        if (mt + 1 < 32)
            stage_wave(stage[(mt + 1) & 1][mq], vp8 + (bbase + (mt + 1) * 4 + mq) * 9216, lane);

        // S^T = K x Q^T
        i32x16 sacc = {};
        #pragma unroll
        for (int s = 0; s < 8; s++)
            sacc = __builtin_amdgcn_mfma_i32_32x32x32_i8(kf[s], qf[s], sacc, 0, 0, 0);

        // dequant -> softsign -> magic-round to i8 (rne), v_perm pack
        float cf[16];
        #pragma unroll
        for (int r = 0; r < 16; r++) {
            float sm = ((const float*)&sg[r >> 2])[r & 3] * srq;
            float xs = (float)sacc[r] * sm;
            float p = xs * __builtin_amdgcn_rcpf(1.0f + fabsf(xs));
            cf[r] = fmaf(p, 127.0f, MAGIC);
        }
        u32 w0 = packlow4(cf[0], cf[1], cf[2], cf[3]);
        u32 w1 = packlow4(cf[4], cf[5], cf[6], cf[7]);
        u32 w2 = packlow4(cf[8], cf[9], cf[10], cf[11]);
        u32 w3 = packlow4(cf[12], cf[13], cf[14], cf[15]);
        u32 x0 = (u32)__shfl_xor((int)w0, 32);
        u32 x1 = (u32)__shfl_xor((int)w1, 32);
        u32 x2 = (u32)__shfl_xor((int)w2, 32);
        u32 x3 = (u32)__shfl_xor((int)w3, 32);
        union { u32 wd[4]; i32x4 v; } pu;
        if (h == 0) { pu.wd[0] = w0; pu.wd[1] = x0; pu.wd[2] = w1; pu.wd[3] = x1; }
        else        { pu.wd[0] = x2; pu.wd[1] = w2; pu.wd[2] = x3; pu.wd[3] = w3; }
        i32x4 pf = pu.v;

        // O += P x Vt + ds, from this wave's private LDS slice
        const u8* vb = stage[mt & 1][mq];
        #pragma unroll
        for (int et = 0; et < 8; et++) {
            i32x4 vf = *(const i32x4*)(vb + et * 1024 + lane * 16);
            oacc[et] = __builtin_amdgcn_mfma_i32_32x32x32_i8(pf, vf, oacc[et], 0, 0, 0);
        }
        {
            i32x4 sf = *(const i32x4*)(vb + 8 * 1024 + lane * 16);
            dsa = __builtin_amdgcn_mfma_i32_32x32x32_i8(pf, sf, dsa, 0, 0, 0);
        }
    }

    // ---- epilogue ----
    // CRITICAL barrier: `red` aliases stage[0][*]. Without this, the fastest wave's
    // red-writes race with slower waves still prefetching/reading stage[0][mq] (R7 bug).
    __syncthreads();

    if (l31 == 0) {
        #pragma unroll
        for (int r = 0; r < 16; r++) dsqi[mq][(r & 3) + 8 * (r >> 2) + 4 * h] = dsa[r];
    }
    int* red = (int*)stage;                    // 32 KB scratch (stage[0] region only)
    if (mq == 3) {
        #pragma unroll
        for (int et = 0; et < 8; et++)
            #pragma unroll
            for (int r = 0; r < 16; r++) {
                int row = (r & 3) + 8 * (r >> 2) + 4 * h;
                red[row * 256 + et * 32 + l31] = oacc[et][r];
            }
    }
    __syncthreads();
    if (mq == 2) {
        #pragma unroll
        for (int et = 0; et < 8; et++)
            #pragma unroll
            for (int r = 0; r < 16; r++) {
                int row = (r & 3) + 8 * (r >> 2) + 4 * h;
                red[row * 256 + et * 32 + l31] += oacc[et][r];
            }
    }
    __syncthreads();
    if (mq == 1) {
        #pragma unroll
        for (int et = 0; et < 8; et++)
            #pragma unroll
            for (int r = 0; r < 16; r++) {
                int row = (r & 3) + 8 * (r >> 2) + 4 * h;
                red[row * 256 + et * 32 + l31] += oacc[et][r];
            }
    }
    __syncthreads();
    if (mq == 0) {
        #pragma unroll
        for (int et = 0; et < 8; et++)
            #pragma unroll
            for (int r = 0; r < 16; r++) {
                int row = (r & 3) + 8 * (r >> 2) + 4 * h;
                int sum = oacc[et][r] + red[row * 256 + et * 32 + l31];
                dval_out[((size_t)(bb * 4096 + q0 + row)) * 256 + et * 32 + l31] = (float)sum * DPV;
            }
        if (lane < 32) {
            int d = dsqi[0][lane] + dsqi[1][lane] + dsqi[2][lane] + dsqi[3][lane];
            ds_out[bb * 4096 + q0 + lane] = (float)d * DST;
        }
    }
}

extern "C" void kernel_launch(void* const* d_in, const int* in_sizes, int n_in,
                              void* d_out, int out_size, void* d_ws, size_t ws_size,
                              hipStream_t stream) {
    const float* val   = (const float*)d_in[0];
    const float* state = (const float*)d_in[1];
    const float* Wv    = (const float*)d_in[2];

    float* ds_out   = (float*)d_out;
    float* dval_out = ds_out + NB * NN;

    u8*  kq8 = (u8*)d_ws;                                      // 4 MB
    u8*  vp8 = kq8 + (size_t)NB * NN * ND;                     // 4.5 MB
    u16* kq  = (u16*)(vp8 + (size_t)NB * 128 * 9216);          // 8 MB
    u16* wv  = kq + (size_t)NB * NN * ND;                      // 128 KB
    float* srow = (float*)(wv + 8 * 16 * 512);                 // 64 KB

    k_prep<<<524, 256, 0, stream>>>(val, state, Wv, kq, kq8, srow, vp8, wv);
    k_pv<<<256, 256, 0, stream>>>(kq, wv, vp8);
    k_main<<<512, 256, 0, stream>>>(kq8, vp8, srow, ds_out, dval_out);
}